// Round 1
// baseline (3481.801 us; speedup 1.0000x reference)
//
#include <hip/hip_runtime.h>
#include <math.h>

// Dims (hardcoded from reference)
// L=8, B=8, N=4, HIN=1024, D=1024, NH=16, KVH=8, HD=64, FF=3072, W=1024, DOUT=1024
// ROPE_THETA=1e6, EPS=1e-6

#define NROWS 32        // B*N
#define DD 1024
#define FFD 3072
#define WIN 1024

// ---------------- generic skinny GEMM: out[32, Ntot] += rms/gate(X)[32,K] @ [W0|W1|W2] ----------------
struct GP {
    const float* X; int ldx;
    const float* W0; const float* W1; const float* W2;
    int n0, n1, n2;      // cols per matrix (multiples of 256)
    int K;
    const float* rmsw;   // null -> no rms
    float* out; int ldo;
    int out_t;           // 1 -> transposed final store out[(b*1024+col)*4+n]
    int gated;           // 1 -> x = silu(X[r][k]) * X[r][3072+k]
};

__global__ __launch_bounds__(256) void gemm_skinny(GP p) {
    __shared__ float s_x[128 * 32];
    __shared__ float s_scale[32];
    __shared__ float s_red[256];
    int tid = threadIdx.x;
    int kbase = blockIdx.y * 128;

    int nb0 = p.n0 >> 8, nb1 = p.n1 >> 8;
    int cb = blockIdx.x; const float* W; int colbase, ldw;
    if (cb < nb0)            { W = p.W0; colbase = 0;           ldw = p.n0; }
    else if (cb < nb0 + nb1) { W = p.W1; colbase = p.n0;        ldw = p.n1; cb -= nb0; }
    else                     { W = p.W2; colbase = p.n0 + p.n1; ldw = p.n2; cb -= nb0 + nb1; }
    int col0 = cb << 8;

    if (p.rmsw) {
        int r = tid >> 3, pp = tid & 7;
        float ss = 0.f;
        for (int k = pp * 4; k < p.K; k += 32) {
            float4 v = *(const float4*)(p.X + (size_t)r * p.ldx + k);
            ss += v.x * v.x + v.y * v.y + v.z * v.z + v.w * v.w;
        }
        s_red[tid] = ss;
        __syncthreads();
        if (tid < 32) {
            float t = 0.f;
            #pragma unroll
            for (int i = 0; i < 8; ++i) t += s_red[tid * 8 + i];
            s_scale[tid] = rsqrtf(t / (float)p.K + 1e-6f);
        }
        __syncthreads();
    }

    { // stage x tile [128 k][32 r], rms / gate applied
        int r = tid & 31;
        int kk0 = (tid >> 5) * 16;
        float scl = p.rmsw ? s_scale[r] : 1.f;
        for (int i = 0; i < 16; ++i) {
            int kk = kk0 + i; int k = kbase + kk;
            float v;
            if (p.gated) {
                float gv = p.X[(size_t)r * p.ldx + k];
                float uv = p.X[(size_t)r * p.ldx + 3072 + k];
                v = gv / (1.f + expf(-gv)) * uv;
            } else {
                v = p.X[(size_t)r * p.ldx + k] * scl;
                if (p.rmsw) v *= p.rmsw[k];
            }
            s_x[kk * 32 + r] = v;
        }
    }
    __syncthreads();

    int tx = tid & 63, ty = tid >> 6;
    int r0 = ty * 8;
    float acc[8][4];
    #pragma unroll
    for (int r = 0; r < 8; ++r)
        #pragma unroll
        for (int c = 0; c < 4; ++c) acc[r][c] = 0.f;

    const float* wp = W + (size_t)kbase * ldw + col0 + tx * 4;
    for (int kk = 0; kk < 128; ++kk) {
        float4 w4 = *(const float4*)wp; wp += ldw;
        float xs[8];
        *(float4*)&xs[0] = *(const float4*)&s_x[kk * 32 + r0];
        *(float4*)&xs[4] = *(const float4*)&s_x[kk * 32 + r0 + 4];
        #pragma unroll
        for (int r = 0; r < 8; ++r) {
            acc[r][0] += xs[r] * w4.x; acc[r][1] += xs[r] * w4.y;
            acc[r][2] += xs[r] * w4.z; acc[r][3] += xs[r] * w4.w;
        }
    }

    #pragma unroll
    for (int r = 0; r < 8; ++r) {
        int row = r0 + r;
        #pragma unroll
        for (int c = 0; c < 4; ++c) {
            int colg = colbase + col0 + tx * 4 + c;
            if (p.out_t)
                atomicAdd(&p.out[((size_t)(row >> 2) * 1024 + colg) * 4 + (row & 3)], acc[r][c]);
            else
                atomicAdd(&p.out[(size_t)row * p.ldo + colg], acc[r][c]);
        }
    }
}

// ---------------- fused KV-cache shift/update + chunked flash-decode attention ----------------
// grid (8 chunks, 8 kv-heads, 8 batch); block 256
__global__ __launch_bounds__(256) void attn_kernel(
    const float* __restrict__ past_k, const float* __restrict__ past_v,
    const float* __restrict__ qkv,    // layer buffer [32][2048]  (q | k | v)
    const float* __restrict__ qn, const float* __restrict__ kn,  // layer slices [64]
    float* __restrict__ outK, float* __restrict__ outV,          // full [L,B,KVH,W,HD]
    float* __restrict__ part, int l)
{
    int c = blockIdx.x, g = blockIdx.y, b = blockIdx.z;
    __shared__ float sK[128][64];
    __shared__ float sV[128][64];
    __shared__ float sQ[8][64];      // combo = qh*4+n, q pre-scaled by 1/8
    __shared__ float sSc[8][128];
    int tid = threadIdx.x;
    int j0 = c * 128;
    const size_t base = ((size_t)(l * 8 + b) * 8 + g) * (size_t)WIN * 64;

    // Phase A: stage shifted K/V window chunk into LDS + write new_ks/new_vs
    int jlim = (c == 7) ? 124 : 128;
    for (int idx = tid; idx < jlim * 16; idx += 256) {
        int j = idx >> 4, f = (idx & 15) * 4;
        int jg = j0 + j;
        float4 k4 = *(const float4*)(past_k + base + (size_t)(jg + 4) * 64 + f);
        float4 v4 = *(const float4*)(past_v + base + (size_t)(jg + 4) * 64 + f);
        *(float4*)&sK[j][f] = k4; *(float4*)&sV[j][f] = v4;
        *(float4*)(outK + base + (size_t)jg * 64 + f) = k4;
        *(float4*)(outV + base + (size_t)jg * 64 + f) = v4;
    }
    if (c == 7) {  // new tokens: k with rms+rope, v plain
        int n = tid >> 6, d = tid & 63;
        float kraw = qkv[(b * 4 + n) * 2048 + 1024 + g * 64 + d];
        float vraw = qkv[(b * 4 + n) * 2048 + 1536 + g * 64 + d];
        float ss = kraw * kraw;
        for (int off = 32; off; off >>= 1) ss += __shfl_xor(ss, off);
        float scl = rsqrtf(ss / 64.f + 1e-6f);
        float kx = kraw * scl * kn[d];
        float kp = __shfl_xor(kx, 32);
        float xr = (d < 32) ? -kp : kp;
        float ang = (float)(1024 + n) * powf(1.0e6f, -(float)(d & 31) / 32.0f);
        float kf = kx * cosf(ang) + xr * sinf(ang);
        int j = 124 + n;
        sK[j][d] = kf; sV[j][d] = vraw;
        outK[base + (size_t)(1020 + n) * 64 + d] = kf;
        outV[base + (size_t)(1020 + n) * 64 + d] = vraw;
    }
    // Phase B: q with rms+rope, 1/sqrt(HD) folded in
    for (int rep = 0; rep < 2; ++rep) {
        int idx = tid + rep * 256;
        int qh = idx >> 8, n = (idx >> 6) & 3, d = idx & 63;
        float qraw = qkv[(b * 4 + n) * 2048 + (2 * g + qh) * 64 + d];
        float ss = qraw * qraw;
        for (int off = 32; off; off >>= 1) ss += __shfl_xor(ss, off);
        float scl = rsqrtf(ss / 64.f + 1e-6f);
        float qx = qraw * scl * qn[d];
        float qp = __shfl_xor(qx, 32);
        float xr = (d < 32) ? -qp : qp;
        float ang = (float)(1024 + n) * powf(1.0e6f, -(float)(d & 31) / 32.0f);
        sQ[qh * 4 + n][d] = (qx * cosf(ang) + xr * sinf(ang)) * 0.125f;
    }
    __syncthreads();

    // Phase C: scores (q held in regs)
    {
        int combo = tid & 7, jg4 = tid >> 3;
        int n = combo & 3;
        float4 qreg[16];
        #pragma unroll
        for (int f = 0; f < 16; ++f) qreg[f] = *(const float4*)&sQ[combo][f * 4];
        #pragma unroll
        for (int jj = 0; jj < 4; ++jj) {
            int j = jg4 * 4 + jj;
            float dot = 0.f;
            #pragma unroll
            for (int f = 0; f < 16; ++f) {
                float4 k4 = *(const float4*)&sK[j][f * 4];
                dot += qreg[f].x * k4.x + qreg[f].y * k4.y + qreg[f].z * k4.z + qreg[f].w * k4.w;
            }
            if (j0 + j > 1020 + n) dot -= 10000.f;   // sliding-window/causal mask
            sSc[combo][j] = dot;
        }
    }
    __syncthreads();

    // Phase D: per-chunk m, sumexp; p written back in place
    float* pslot = part + (size_t)(((b * 8 + g) * 8 + c) * 8) * 66;
    if (tid < 8) {
        int combo = tid;
        float m = -1e30f;
        for (int j = 0; j < 128; ++j) m = fmaxf(m, sSc[combo][j]);
        float s = 0.f;
        for (int j = 0; j < 128; ++j) { float pe = expf(sSc[combo][j] - m); sSc[combo][j] = pe; s += pe; }
        pslot[combo * 66 + 0] = m; pslot[combo * 66 + 1] = s;
    }
    __syncthreads();

    // Phase E: partial P*V
    {
        int combo = tid & 7, d = (tid >> 3) * 2;
        float a0 = 0.f, a1 = 0.f;
        for (int j = 0; j < 128; ++j) {
            float pe = sSc[combo][j];
            a0 += pe * sV[j][d]; a1 += pe * sV[j][d + 1];
        }
        pslot[combo * 66 + 2 + d] = a0;
        pslot[combo * 66 + 3 + d] = a1;
    }
}

// combine 8 chunk-partials -> o rows [32, 1024]; grid 128 = (b, head)
__global__ __launch_bounds__(256) void attn_reduce(const float* __restrict__ part, float* __restrict__ obuf) {
    int b = blockIdx.x >> 4, h = blockIdx.x & 15;
    int g = h >> 1, qh = h & 1;
    int tid = threadIdx.x; int n = tid >> 6, d = tid & 63;
    int combo = qh * 4 + n;
    float M = -1e30f;
    for (int c = 0; c < 8; ++c)
        M = fmaxf(M, part[(size_t)(((b * 8 + g) * 8 + c) * 8 + combo) * 66]);
    float S = 0.f, o = 0.f;
    for (int c = 0; c < 8; ++c) {
        const float* ps = part + (size_t)(((b * 8 + g) * 8 + c) * 8 + combo) * 66;
        float w = expf(ps[0] - M);
        S += ps[1] * w;
        o += ps[2 + d] * w;
    }
    obuf[(b * 4 + n) * 1024 + h * 64 + d] = o / S;
}

// ---------------- launch ----------------
extern "C" void kernel_launch(void* const* d_in, const int* in_sizes, int n_in,
                              void* d_out, int out_size, void* d_ws, size_t ws_size,
                              hipStream_t stream) {
    const float* hidden = (const float*)d_in[0];
    const float* past_k = (const float*)d_in[1];
    const float* past_v = (const float*)d_in[2];
    const float* Win    = (const float*)d_in[3];
    const float* Wout   = (const float*)d_in[4];
    const float* norm_w = (const float*)d_in[5];
    const float* Wq     = (const float*)d_in[6];
    const float* Wk     = (const float*)d_in[7];
    const float* Wv     = (const float*)d_in[8];
    const float* Wo     = (const float*)d_in[9];
    const float* ln1    = (const float*)d_in[10];
    const float* ln2    = (const float*)d_in[11];
    const float* qn     = (const float*)d_in[12];
    const float* kn     = (const float*)d_in[13];
    const float* Wg     = (const float*)d_in[14];
    const float* Wu     = (const float*)d_in[15];
    const float* Wd     = (const float*)d_in[16];

    float* out  = (float*)d_out;
    float* ws   = (float*)d_ws;

    // ws layout (floats)
    float* h    = ws;                         // 32*1024
    float* obuf = ws + 32768;                 // 32*1024
    float* qkv  = ws + 65536;                 // 8 * 32*2048
    float* gu   = ws + 589824;                // 8 * 32*6144
    float* part = ws + 2162688;               // 8*8*8*8*66 = 270336
    // total ~2.43M floats (~9.7 MB)

    // zero accumulation buffers (h, qkv, gu) and the new_hidden output slot
    hipMemsetAsync(d_ws, 0, (size_t)2162688 * sizeof(float), stream);
    hipMemsetAsync(d_out, 0, (size_t)32768 * sizeof(float), stream);

    float* outK = out + 32768;
    float* outV = outK + (size_t)8 * 8 * 8 * 1024 * 64;

    // h0 = hidden @ Win
    {
        GP p{}; p.X = hidden; p.ldx = 1024; p.W0 = Win; p.n0 = 1024; p.K = 1024;
        p.out = h; p.ldo = 1024;
        gemm_skinny<<<dim3(4, 8), 256, 0, stream>>>(p);
    }

    for (int l = 0; l < 8; ++l) {
        float* qkv_l = qkv + (size_t)l * 65536;
        float* gu_l  = gu  + (size_t)l * 196608;

        // QKV projection, rms(ln1) fused
        {
            GP p{}; p.X = h; p.ldx = 1024;
            p.W0 = Wq + (size_t)l * 1024 * 1024; p.n0 = 1024;
            p.W1 = Wk + (size_t)l * 1024 * 512;  p.n1 = 512;
            p.W2 = Wv + (size_t)l * 1024 * 512;  p.n2 = 512;
            p.K = 1024; p.rmsw = ln1 + l * 1024;
            p.out = qkv_l; p.ldo = 2048;
            gemm_skinny<<<dim3(8, 8), 256, 0, stream>>>(p);
        }
        // fused cache shift + attention partials
        attn_kernel<<<dim3(8, 8, 8), 256, 0, stream>>>(past_k, past_v, qkv_l,
                                                       qn + l * 64, kn + l * 64,
                                                       outK, outV, part, l);
        attn_reduce<<<dim3(128), 256, 0, stream>>>(part, obuf);
        // O projection + residual into h
        {
            GP p{}; p.X = obuf; p.ldx = 1024;
            p.W0 = Wo + (size_t)l * 1024 * 1024; p.n0 = 1024;
            p.K = 1024; p.out = h; p.ldo = 1024;
            gemm_skinny<<<dim3(4, 8), 256, 0, stream>>>(p);
        }
        // gate+up, rms(ln2) fused
        {
            GP p{}; p.X = h; p.ldx = 1024;
            p.W0 = Wg + (size_t)l * 1024 * 3072; p.n0 = 3072;
            p.W1 = Wu + (size_t)l * 1024 * 3072; p.n1 = 3072;
            p.K = 1024; p.rmsw = ln2 + l * 1024;
            p.out = gu_l; p.ldo = 6144;
            gemm_skinny<<<dim3(24, 8), 256, 0, stream>>>(p);
        }
        // down projection, silu-gating fused, residual into h
        {
            GP p{}; p.X = gu_l; p.ldx = 6144; p.gated = 1;
            p.W0 = Wd + (size_t)l * 3072 * 1024; p.n0 = 1024;
            p.K = 3072; p.out = h; p.ldo = 1024;
            gemm_skinny<<<dim3(4, 24), 256, 0, stream>>>(p);
        }
    }

    // final norm + Wout, transposed store into new_hidden [B, DOUT, N]
    {
        GP p{}; p.X = h; p.ldx = 1024; p.W0 = Wout; p.n0 = 1024; p.K = 1024;
        p.rmsw = norm_w; p.out = out; p.out_t = 1;
        gemm_skinny<<<dim3(4, 8), 256, 0, stream>>>(p);
    }
}